// Round 3
// baseline (469.121 us; speedup 1.0000x reference)
//
#include <hip/hip_runtime.h>
#include <hip/hip_bf16.h>
#include <math.h>

// Problem constants
#define B_  64
#define T_  2048
#define DEC_ 1024
#define ENC_ 512
#define ATT_ 128
#define LOC_ 32
#define KW_  31

typedef __attribute__((ext_vector_type(8))) short short8;
typedef __attribute__((ext_vector_type(4))) float f32x4;
typedef __attribute__((ext_vector_type(4))) unsigned int u32x4;

__device__ inline unsigned short bf16_rn(float x) {
    unsigned int u = __builtin_bit_cast(unsigned int, x);
    unsigned int r = u + 0x7fffu + ((u >> 16) & 1u);
    return (unsigned short)(r >> 16);
}
__device__ inline float bf16_to_f(unsigned short h) {
    unsigned int u = ((unsigned int)h) << 16;
    return __builtin_bit_cast(float, u);
}

// Split 8 floats into hi/lo bf16 fragments. BIT-EXACT to R1's cvt_pair
// (same add-based RNE, same residual), but packs pairs with shift/and-or
// instead of per-element short8 insertion (~35% fewer VALU ops).
__device__ inline void cvt_split8_exact(const float* f, short8& hi8, short8& lo8) {
    u32x4 hw, lw;
    #pragma unroll
    for (int p = 0; p < 4; ++p) {
        float a = f[2 * p], b2 = f[2 * p + 1];
        unsigned u0 = __builtin_bit_cast(unsigned, a);
        unsigned u1 = __builtin_bit_cast(unsigned, b2);
        unsigned r0 = u0 + 0x7fffu + ((u0 >> 16) & 1u);
        unsigned r1 = u1 + 0x7fffu + ((u1 >> 16) & 1u);
        hw[p] = (r0 >> 16) | (r1 & 0xffff0000u);
        float d0 = a  - __builtin_bit_cast(float, r0 & 0xffff0000u);
        float d1 = b2 - __builtin_bit_cast(float, r1 & 0xffff0000u);
        unsigned v0 = __builtin_bit_cast(unsigned, d0);
        unsigned v1 = __builtin_bit_cast(unsigned, d1);
        unsigned s0 = v0 + 0x7fffu + ((v0 >> 16) & 1u);
        unsigned s1 = v1 + 0x7fffu + ((v1 >> 16) & 1u);
        lw[p] = (s0 >> 16) | (s1 & 0xffff0000u);
    }
    hi8 = __builtin_bit_cast(short8, hw);
    lo8 = __builtin_bit_cast(short8, lw);
}

// ---------------------------------------------------------------------------
// K1: prep (unchanged)
// ---------------------------------------------------------------------------
__global__ __launch_bounds__(256) void prep_kernel(
    const float* __restrict__ query, const float* __restrict__ Q_w,
    const float* __restrict__ Q_b, const float* __restrict__ conv_w,
    const float* __restrict__ loc_proj_w, const float* __restrict__ V_w,
    float* __restrict__ qbuf,
    unsigned short* __restrict__ Bph, unsigned short* __restrict__ Bpl,
    unsigned short* __restrict__ effh, unsigned short* __restrict__ effl)
{
    int bi = blockIdx.x, tid = threadIdx.x;
    if (bi < 256) {
        int b = bi >> 2, grp = bi & 3;
        __shared__ float sq[DEC_];
        *(float4*)(&sq[tid * 4]) = *(const float4*)(query + (size_t)b * DEC_ + tid * 4);
        __syncthreads();
        int w = tid >> 6, lane = tid & 63;
        int a0 = grp * 32 + w * 8;
        for (int p = 0; p < 4; ++p) {
            int a = a0 + 2 * p;
            const float* r0 = Q_w + (size_t)a * DEC_;
            const float* r1 = r0 + DEC_;
            float s0 = 0.f, s1 = 0.f;
            #pragma unroll
            for (int i = 0; i < 4; ++i) {
                float4 q0 = *(const float4*)(r0 + i * 256 + lane * 4);
                float4 q1 = *(const float4*)(r1 + i * 256 + lane * 4);
                float4 xq = *(const float4*)(sq + i * 256 + lane * 4);
                s0 += q0.x * xq.x + q0.y * xq.y + q0.z * xq.z + q0.w * xq.w;
                s1 += q1.x * xq.x + q1.y * xq.y + q1.z * xq.z + q1.w * xq.w;
            }
            #pragma unroll
            for (int m = 32; m >= 1; m >>= 1) {
                s0 += __shfl_xor(s0, m, 64);
                s1 += __shfl_xor(s1, m, 64);
            }
            if (lane == 0) {
                qbuf[b * ATT_ + a]     = s0 + Q_b[a];
                qbuf[b * ATT_ + a + 1] = s1 + Q_b[a + 1];
            }
        }
    } else if (bi == 256) {
        __shared__ float slp[ATT_ * LOC_];
        __shared__ float scw[LOC_ * KW_];
        for (int i = tid; i < ATT_ * LOC_; i += 256) slp[i] = loc_proj_w[i];
        for (int i = tid; i < LOC_ * KW_; i += 256) scw[i] = conv_w[i];
        __syncthreads();
        if (tid < ATT_) {
            int n = tid;
            for (int k = 0; k < 32; ++k) {
                float s = 0.f;
                if (k < KW_)
                    #pragma unroll
                    for (int c = 0; c < LOC_; ++c)
                        s += slp[n * LOC_ + c] * scw[c * KW_ + k];
                unsigned short h = bf16_rn(s);
                effh[n * 32 + k] = h;
                effl[n * 32 + k] = bf16_rn(s - bf16_to_f(h));
            }
        }
    } else {
        int g0 = (bi - 257) * 512;
        #pragma unroll
        for (int p = 0; p < 2; ++p) {
            int gi = g0 + p * 256 + tid;
            int n  = gi >> 7;
            int kq = (gi & 127) * 4;
            float4 v = ((const float4*)V_w)[gi];
            ushort4 h4, l4;
            h4.x = bf16_rn(v.x); l4.x = bf16_rn(v.x - bf16_to_f(h4.x));
            h4.y = bf16_rn(v.y); l4.y = bf16_rn(v.y - bf16_to_f(h4.y));
            h4.z = bf16_rn(v.z); l4.z = bf16_rn(v.z - bf16_to_f(h4.z));
            h4.w = bf16_rn(v.w); l4.w = bf16_rn(v.w - bf16_to_f(h4.w));
            int dst = (kq >> 5) * 4096 + n * 32 + (kq & 31);
            *(ushort4*)(Bph + dst) = h4;
            *(ushort4*)(Bpl + dst) = l4;
        }
    }
}

// ---------------------------------------------------------------------------
// K2 (FUSED): energies (split-bf16 MFMA, 2-deep HBM prefetch, bit-exact cvt)
// + flash-style local softmax + partial context (L2-resident re-read).
// Numerics are BIT-IDENTICAL to the R1 passing kernel.
// ---------------------------------------------------------------------------
__global__ __launch_bounds__(256, 2) void energy_ctx_kernel(
    const float* __restrict__ values, const float* __restrict__ cum,
    const float* __restrict__ qbuf,
    const unsigned short* __restrict__ Bph, const unsigned short* __restrict__ Bpl,
    const unsigned short* __restrict__ effh, const unsigned short* __restrict__ effl,
    const float* __restrict__ vw, const unsigned char* __restrict__ mask,
    float* __restrict__ wU, float* __restrict__ bstats,
    float* __restrict__ ctxpart)
{
    __shared__ float sx[160];
    __shared__ float se[128];
    __shared__ float red[512];

    const int tid = threadIdx.x;
    const int bx  = blockIdx.x;
    const int b   = bx >> 4;
    const int t0  = (bx & 15) * 128;

    if (tid < 160) {
        int g = t0 - 15 + tid;
        sx[tid] = (g >= 0 && g < T_) ? cum[b * T_ + g] : 0.f;
    }
    __syncthreads();

    const int w      = tid >> 6;
    const int lane   = tid & 63;
    const int lane15 = lane & 15;
    const int quad   = lane >> 4;

    f32x4 acc[2][8];
    #pragma unroll
    for (int i = 0; i < 2; ++i)
        #pragma unroll
        for (int j = 0; j < 8; ++j) acc[i][j] = (f32x4){0.f, 0.f, 0.f, 0.f};

    const float* abase = values + ((size_t)b * T_ + t0 + w * 32 + lane15) * ENC_ + quad * 8;
    const unsigned short* bbh = Bph + lane15 * 32 + quad * 8;
    const unsigned short* bbl = Bpl + lane15 * 32 + quad * 8;

    // 2-deep prefetch: pfA holds chunk kc, pfB holds chunk kc+32.
    float4 pfA[2][2], pfB[2][2];
    #pragma unroll
    for (int i = 0; i < 2; ++i) {
        pfA[i][0] = *(const float4*)(abase + i * 16 * ENC_);
        pfA[i][1] = *(const float4*)(abase + i * 16 * ENC_ + 4);
        pfB[i][0] = *(const float4*)(abase + i * 16 * ENC_ + 32);
        pfB[i][1] = *(const float4*)(abase + i * 16 * ENC_ + 36);
    }

    auto halfstep = [&](float4 (&pfX)[2][2], int kc, bool pre) {
        // A fragments from registers (loaded 2 chunks ago)
        short8 ah[2], al[2];
        #pragma unroll
        for (int i = 0; i < 2; ++i) {
            float fb[8] = {pfX[i][0].x, pfX[i][0].y, pfX[i][0].z, pfX[i][0].w,
                           pfX[i][1].x, pfX[i][1].y, pfX[i][1].z, pfX[i][1].w};
            cvt_split8_exact(fb, ah[i], al[i]);
        }
        // B fragments (L2) issued BEFORE the HBM prefetch (vmcnt in-order:
        // waiting on B leaves the later-issued A-prefetch in flight)
        short8 bh[8], bl[8];
        const unsigned short* bb_h = bbh + (kc >> 5) * 4096;
        const unsigned short* bb_l = bbl + (kc >> 5) * 4096;
        #pragma unroll
        for (int j = 0; j < 8; ++j) {
            bh[j] = *(const short8*)(bb_h + j * 512);
            bl[j] = *(const short8*)(bb_l + j * 512);
        }
        __builtin_amdgcn_sched_barrier(0);
        if (pre) {
            #pragma unroll
            for (int i = 0; i < 2; ++i) {
                pfX[i][0] = *(const float4*)(abase + i * 16 * ENC_ + kc + 64);
                pfX[i][1] = *(const float4*)(abase + i * 16 * ENC_ + kc + 68);
            }
        }
        __builtin_amdgcn_sched_barrier(0);
        #pragma unroll
        for (int j = 0; j < 8; ++j)
            #pragma unroll
            for (int i = 0; i < 2; ++i) {
                acc[i][j] = __builtin_amdgcn_mfma_f32_16x16x32_bf16(ah[i], bh[j], acc[i][j], 0, 0, 0);
                acc[i][j] = __builtin_amdgcn_mfma_f32_16x16x32_bf16(ah[i], bl[j], acc[i][j], 0, 0, 0);
                acc[i][j] = __builtin_amdgcn_mfma_f32_16x16x32_bf16(al[i], bh[j], acc[i][j], 0, 0, 0);
            }
    };

    for (int kc = 0; kc < ENC_; kc += 64) {
        halfstep(pfA, kc,      kc + 64 < ENC_);
        halfstep(pfB, kc + 32, kc + 96 < ENC_);
    }

    // ---- loc conv as MFMA: A' Toeplitz built from sx in-register ----
    {
        short8 ah[2], al[2];
        #pragma unroll
        for (int i = 0; i < 2; ++i) {
            int base = w * 32 + i * 16 + lane15 + quad * 8;
            float xv[8];
            #pragma unroll
            for (int j2 = 0; j2 < 8; ++j2) xv[j2] = sx[base + j2];
            cvt_split8_exact(xv, ah[i], al[i]);
        }
        #pragma unroll
        for (int j = 0; j < 8; ++j) {
            int n = j * 16 + lane15;
            short8 bh = *(const short8*)(effh + n * 32 + quad * 8);
            short8 bl = *(const short8*)(effl + n * 32 + quad * 8);
            #pragma unroll
            for (int i = 0; i < 2; ++i) {
                acc[i][j] = __builtin_amdgcn_mfma_f32_16x16x32_bf16(ah[i], bh, acc[i][j], 0, 0, 0);
                acc[i][j] = __builtin_amdgcn_mfma_f32_16x16x32_bf16(ah[i], bl, acc[i][j], 0, 0, 0);
                acc[i][j] = __builtin_amdgcn_mfma_f32_16x16x32_bf16(al[i], bh, acc[i][j], 0, 0, 0);
            }
        }
    }

    // ---- energies: E[t] = sum_n vw[n]*tanhf(acc + q[n]) -> LDS se[128] ----
    float qv[8], vv[8];
    #pragma unroll
    for (int j = 0; j < 8; ++j) {
        int n = j * 16 + lane15;
        qv[j] = qbuf[b * ATT_ + n];
        vv[j] = vw[n];
    }
    #pragma unroll
    for (int i = 0; i < 2; ++i)
        #pragma unroll
        for (int r = 0; r < 4; ++r) {
            float s = 0.f;
            #pragma unroll
            for (int j = 0; j < 8; ++j)
                s += vv[j] * tanhf(acc[i][j][r] + qv[j]);
            #pragma unroll
            for (int m = 8; m >= 1; m >>= 1) s += __shfl_xor(s, m, 64);
            if (lane15 == 0)
                se[w * 32 + i * 16 + quad * 4 + r] = s;
        }
    __syncthreads();

    // ---- mask, then local (chunk) max + sum ----
    if (tid < 128 && mask[b * T_ + t0 + tid]) se[tid] = -INFINITY;
    __syncthreads();

    float e0 = se[lane * 2], e1 = se[lane * 2 + 1];
    float mx = fmaxf(e0, e1);
    #pragma unroll
    for (int m = 32; m >= 1; m >>= 1) mx = fmaxf(mx, __shfl_xor(mx, m, 64));
    float w0 = 0.f, w1 = 0.f;
    if (mx > -INFINITY) {
        w0 = expf(e0 - mx);
        w1 = expf(e1 - mx);
    }
    float sm = w0 + w1;
    #pragma unroll
    for (int m = 32; m >= 1; m >>= 1) sm += __shfl_xor(sm, m, 64);
    __syncthreads();

    if (w == 0) {
        se[lane * 2]     = w0;
        se[lane * 2 + 1] = w1;
        *(float2*)(wU + b * T_ + t0 + lane * 2) = make_float2(w0, w1);
        if (lane == 0)
            *(float2*)(bstats + bx * 2) = make_float2(mx, sm);
    }
    __syncthreads();

    // ---- partial context (chunk is L2/L3-resident) ----
    {
        int tt = tid >> 7;
        int e4 = (tid & 127) * 4;
        const float* vp = values + ((size_t)b * T_ + t0 + tt * 64) * ENC_ + e4;
        float4 cacc = make_float4(0.f, 0.f, 0.f, 0.f);
        #pragma unroll 8
        for (int t = 0; t < 64; ++t) {
            float4 v = *(const float4*)(vp + (size_t)t * ENC_);
            float wv = se[tt * 64 + t];
            cacc.x += wv * v.x; cacc.y += wv * v.y;
            cacc.z += wv * v.z; cacc.w += wv * v.w;
        }
        if (tt == 1) *(float4*)&red[e4] = cacc;
        __syncthreads();
        if (tt == 0) {
            float4 o = *(const float4*)&red[e4];
            float4 tot = make_float4(cacc.x + o.x, cacc.y + o.y,
                                     cacc.z + o.z, cacc.w + o.w);
            *(float4*)(ctxpart + (size_t)bx * ENC_ + e4) = tot;
        }
    }
}

// ---------------------------------------------------------------------------
// K3: combine 16 chunk-partials per b (unchanged)
// ---------------------------------------------------------------------------
__global__ __launch_bounds__(256) void combine_kernel(
    const float* __restrict__ bstats, const float* __restrict__ ctxpart,
    const float* __restrict__ wU, float* __restrict__ out)
{
    int b = blockIdx.x, tid = threadIdx.x;
    __shared__ float smx[16], ssm[16], ssc[16];
    if (tid < 16) {
        float2 st = *(const float2*)(bstats + (b * 16 + tid) * 2);
        smx[tid] = st.x; ssm[tid] = st.y;
    }
    __syncthreads();
    float M = -INFINITY;
    #pragma unroll
    for (int k = 0; k < 16; ++k) M = fmaxf(M, smx[k]);
    if (tid < 16)
        ssc[tid] = (smx[tid] > -INFINITY) ? expf(smx[tid] - M) : 0.f;
    __syncthreads();
    float S = 0.f;
    #pragma unroll
    for (int k = 0; k < 16; ++k) S += ssm[k] * ssc[k];
    float invS = 1.f / S;

    float* ctx  = out;
    float* wout = out + B_ * ENC_;

    float cx = 0.f, cy = 0.f;
    #pragma unroll
    for (int k = 0; k < 16; ++k) {
        float2 v = *(const float2*)(ctxpart + (size_t)(b * 16 + k) * ENC_ + tid * 2);
        cx += v.x * ssc[k]; cy += v.y * ssc[k];
    }
    *(float2*)(ctx + b * ENC_ + tid * 2) = make_float2(cx * invS, cy * invS);

    #pragma unroll
    for (int p = 0; p < 8; ++p) {
        int t = p * 256 + tid;
        wout[b * T_ + t] = wU[b * T_ + t] * ssc[t >> 7] * invS;
    }
}

// ---------------------------------------------------------------------------
extern "C" void kernel_launch(void* const* d_in, const int* in_sizes, int n_in,
                              void* d_out, int out_size, void* d_ws, size_t ws_size,
                              hipStream_t stream) {
    const float* query        = (const float*)d_in[0];
    const float* values       = (const float*)d_in[1];
    const float* cum          = (const float*)d_in[2];
    const unsigned char* mask = (const unsigned char*)d_in[3];
    const float* Q_w          = (const float*)d_in[4];
    const float* Q_b          = (const float*)d_in[5];
    const float* V_w          = (const float*)d_in[6];
    const float* conv_w       = (const float*)d_in[7];
    const float* loc_proj_w   = (const float*)d_in[8];
    const float* v_w          = (const float*)d_in[9];

    float* out = (float*)d_out;
    char*  ws  = (char*)d_ws;
    // ws layout (bytes):
    //  qbuf @0 (32 KB) | Bph @32768 (128 KB) | Bpl @163840 (128 KB)
    //  effh @294912 (8 KB) | effl @303104 (8 KB) | wU @311296 (512 KB)
    //  bstats @835584 (8 KB) | ctxpart @843776 (2 MB)
    float*          qbuf     = (float*)(ws);
    unsigned short* Bph      = (unsigned short*)(ws + 32768);
    unsigned short* Bpl      = (unsigned short*)(ws + 163840);
    unsigned short* effh     = (unsigned short*)(ws + 294912);
    unsigned short* effl     = (unsigned short*)(ws + 303104);
    float*          wU       = (float*)(ws + 311296);
    float*          bstats   = (float*)(ws + 835584);
    float*          ctxpart  = (float*)(ws + 843776);

    prep_kernel<<<289, 256, 0, stream>>>(query, Q_w, Q_b, conv_w, loc_proj_w, V_w,
                                         qbuf, Bph, Bpl, effh, effl);
    energy_ctx_kernel<<<1024, 256, 0, stream>>>(values, cum, qbuf, Bph, Bpl,
                                                effh, effl, v_w, mask,
                                                wU, bstats, ctxpart);
    combine_kernel<<<B_, 256, 0, stream>>>(bstats, ctxpart, wU, out);
}

// Round 4
// 460.271 us; speedup vs baseline: 1.0192x; 1.0192x over previous
//
#include <hip/hip_runtime.h>
#include <hip/hip_bf16.h>
#include <math.h>

// Problem constants
#define B_  64
#define T_  2048
#define DEC_ 1024
#define ENC_ 512
#define ATT_ 128
#define LOC_ 32
#define KW_  31

typedef __attribute__((ext_vector_type(8))) short short8;
typedef __attribute__((ext_vector_type(4))) float f32x4;
typedef __attribute__((ext_vector_type(4))) unsigned int u32x4;

__device__ inline unsigned short bf16_rn(float x) {
    unsigned int u = __builtin_bit_cast(unsigned int, x);
    unsigned int r = u + 0x7fffu + ((u >> 16) & 1u);
    return (unsigned short)(r >> 16);
}
__device__ inline float bf16_to_f(unsigned short h) {
    unsigned int u = ((unsigned int)h) << 16;
    return __builtin_bit_cast(float, u);
}

// Split 8 floats into hi/lo bf16 (bit-exact add-based RNE, packed pairs).
__device__ inline void cvt_split8_exact(const float* f, short8& hi8, short8& lo8) {
    u32x4 hw, lw;
    #pragma unroll
    for (int p = 0; p < 4; ++p) {
        float a = f[2 * p], b2 = f[2 * p + 1];
        unsigned u0 = __builtin_bit_cast(unsigned, a);
        unsigned u1 = __builtin_bit_cast(unsigned, b2);
        unsigned r0 = u0 + 0x7fffu + ((u0 >> 16) & 1u);
        unsigned r1 = u1 + 0x7fffu + ((u1 >> 16) & 1u);
        hw[p] = (r0 >> 16) | (r1 & 0xffff0000u);
        float d0 = a  - __builtin_bit_cast(float, r0 & 0xffff0000u);
        float d1 = b2 - __builtin_bit_cast(float, r1 & 0xffff0000u);
        unsigned v0 = __builtin_bit_cast(unsigned, d0);
        unsigned v1 = __builtin_bit_cast(unsigned, d1);
        unsigned s0 = v0 + 0x7fffu + ((v0 >> 16) & 1u);
        unsigned s1 = v1 + 0x7fffu + ((v1 >> 16) & 1u);
        lw[p] = (s0 >> 16) | (s1 & 0xffff0000u);
    }
    hi8 = __builtin_bit_cast(short8, hw);
    lo8 = __builtin_bit_cast(short8, lw);
}

// ---------------------------------------------------------------------------
// K1: prep. V_w branch now writes Bpk in staging order (fragment-lane-major):
//   ushort offset = c*8192 + s*4096 + j*512 + l*8 + e
//   c = k/32 chunk, s = hi/lo, j = n/16, l = ((k&31)>>3)*16 + (n&15), e = k&7
// so the energy kernel can global_load_lds it linearly (base + lane*16B).
// ---------------------------------------------------------------------------
__global__ __launch_bounds__(256) void prep_kernel(
    const float* __restrict__ query, const float* __restrict__ Q_w,
    const float* __restrict__ Q_b, const float* __restrict__ conv_w,
    const float* __restrict__ loc_proj_w, const float* __restrict__ V_w,
    float* __restrict__ qbuf, unsigned short* __restrict__ Bpk,
    unsigned short* __restrict__ effh, unsigned short* __restrict__ effl)
{
    int bi = blockIdx.x, tid = threadIdx.x;
    if (bi < 256) {
        int b = bi >> 2, grp = bi & 3;
        __shared__ float sq[DEC_];
        *(float4*)(&sq[tid * 4]) = *(const float4*)(query + (size_t)b * DEC_ + tid * 4);
        __syncthreads();
        int w = tid >> 6, lane = tid & 63;
        int a0 = grp * 32 + w * 8;
        for (int p = 0; p < 4; ++p) {
            int a = a0 + 2 * p;
            const float* r0 = Q_w + (size_t)a * DEC_;
            const float* r1 = r0 + DEC_;
            float s0 = 0.f, s1 = 0.f;
            #pragma unroll
            for (int i = 0; i < 4; ++i) {
                float4 q0 = *(const float4*)(r0 + i * 256 + lane * 4);
                float4 q1 = *(const float4*)(r1 + i * 256 + lane * 4);
                float4 xq = *(const float4*)(sq + i * 256 + lane * 4);
                s0 += q0.x * xq.x + q0.y * xq.y + q0.z * xq.z + q0.w * xq.w;
                s1 += q1.x * xq.x + q1.y * xq.y + q1.z * xq.z + q1.w * xq.w;
            }
            #pragma unroll
            for (int m = 32; m >= 1; m >>= 1) {
                s0 += __shfl_xor(s0, m, 64);
                s1 += __shfl_xor(s1, m, 64);
            }
            if (lane == 0) {
                qbuf[b * ATT_ + a]     = s0 + Q_b[a];
                qbuf[b * ATT_ + a + 1] = s1 + Q_b[a + 1];
            }
        }
    } else if (bi == 256) {
        __shared__ float slp[ATT_ * LOC_];
        __shared__ float scw[LOC_ * KW_];
        for (int i = tid; i < ATT_ * LOC_; i += 256) slp[i] = loc_proj_w[i];
        for (int i = tid; i < LOC_ * KW_; i += 256) scw[i] = conv_w[i];
        __syncthreads();
        if (tid < ATT_) {
            int n = tid;
            for (int k = 0; k < 32; ++k) {
                float s = 0.f;
                if (k < KW_)
                    #pragma unroll
                    for (int c = 0; c < LOC_; ++c)
                        s += slp[n * LOC_ + c] * scw[c * KW_ + k];
                unsigned short h = bf16_rn(s);
                effh[n * 32 + k] = h;
                effl[n * 32 + k] = bf16_rn(s - bf16_to_f(h));
            }
        }
    } else {
        int g0 = (bi - 257) * 512;
        #pragma unroll
        for (int p = 0; p < 2; ++p) {
            int gi = g0 + p * 256 + tid;
            int n  = gi >> 7;
            int kq = (gi & 127) * 4;
            float4 v = ((const float4*)V_w)[gi];
            ushort4 h4, l4;
            h4.x = bf16_rn(v.x); l4.x = bf16_rn(v.x - bf16_to_f(h4.x));
            h4.y = bf16_rn(v.y); l4.y = bf16_rn(v.y - bf16_to_f(h4.y));
            h4.z = bf16_rn(v.z); l4.z = bf16_rn(v.z - bf16_to_f(h4.z));
            h4.w = bf16_rn(v.w); l4.w = bf16_rn(v.w - bf16_to_f(h4.w));
            int c = kq >> 5;
            int j = n >> 7 == 0 ? (n >> 4) : (n >> 4);   // j = n/16
            int l = ((kq & 31) >> 3) * 16 + (n & 15);
            int e = kq & 7;
            int dst = c * 8192 + (n >> 4) * 512 + l * 8 + e;
            (void)j;
            *(ushort4*)(Bpk + dst)        = h4;
            *(ushort4*)(Bpk + dst + 4096) = l4;
        }
    }
}

// ---------------------------------------------------------------------------
// K2 (FUSED): split-bf16 MFMA energies with B double-buffered in LDS via
// global_load_lds (counted vmcnt, raw s_barrier — A-prefetch stays in
// flight), then flash local softmax + partial context (L2-resident re-read).
// GEMM accumulation order identical to R3 (bit-exact numerics).
// ---------------------------------------------------------------------------
__global__ __launch_bounds__(256, 2) void energy_ctx_kernel(
    const float* __restrict__ values, const float* __restrict__ cum,
    const float* __restrict__ qbuf, const unsigned short* __restrict__ Bpk,
    const unsigned short* __restrict__ effh, const unsigned short* __restrict__ effl,
    const float* __restrict__ vw, const unsigned char* __restrict__ mask,
    float* __restrict__ wU, float* __restrict__ bstats,
    float* __restrict__ ctxpart)
{
    __shared__ unsigned short sB[2][8192];   // 2 x (hi 8KB | lo 8KB)
    __shared__ float sx[160];
    __shared__ float se[128];
    __shared__ float red[512];

    const int tid = threadIdx.x;
    const int bx  = blockIdx.x;
    const int b   = bx >> 4;
    const int t0  = (bx & 15) * 128;

    if (tid < 160) {
        int g = t0 - 15 + tid;
        sx[tid] = (g >= 0 && g < T_) ? cum[b * T_ + g] : 0.f;
    }
    __syncthreads();   // full drain: sx ready, vmcnt clean before staging

    const int w      = tid >> 6;
    const int lane   = tid & 63;
    const int lane15 = lane & 15;
    const int quad   = lane >> 4;

    f32x4 acc[2][8];
    #pragma unroll
    for (int i = 0; i < 2; ++i)
        #pragma unroll
        for (int j = 0; j < 8; ++j) acc[i][j] = (f32x4){0.f, 0.f, 0.f, 0.f};

    const float* abase = values + ((size_t)b * T_ + t0 + w * 32 + lane15) * ENC_ + quad * 8;

    // stage chunk c of Bpk into sB[buf]: 4 waves x 4 x global_load_lds(16B)
    auto stageB = [&](int buf, int c) {
        const unsigned short* src = Bpk + c * 8192 + w * 512 + lane * 8;
        #pragma unroll
        for (int r = 0; r < 4; ++r) {
            __builtin_amdgcn_global_load_lds(
                (const __attribute__((address_space(1))) unsigned int*)(src + r * 2048),
                (__attribute__((address_space(3))) unsigned int*)(&sB[buf][r * 2048 + w * 512]),
                16, 0, 0);
        }
    };

    float4 pf[2][2];
    // prologue: stage chunk 0, then issue A(0) (stage older than pf in vmcnt)
    stageB(0, 0);
    __builtin_amdgcn_sched_barrier(0);
    #pragma unroll
    for (int i = 0; i < 2; ++i) {
        pf[i][0] = *(const float4*)(abase + i * 16 * ENC_);
        pf[i][1] = *(const float4*)(abase + i * 16 * ENC_ + 4);
    }
    __builtin_amdgcn_sched_barrier(0);
    asm volatile("s_waitcnt vmcnt(4)");      // stage(0) done; A(0) in flight
    __builtin_amdgcn_sched_barrier(0);
    __builtin_amdgcn_s_barrier();

    int cur = 0;
    for (int c = 0; c < 16; ++c) {
        // 1) stage next chunk (oldest vmem ops of this iteration)
        if (c + 1 < 16) stageB(cur ^ 1, c + 1);
        __builtin_amdgcn_sched_barrier(0);

        // 2) cvt A (waits on pf loads from last iter; compiler-counted)
        short8 ah[2], al[2];
        #pragma unroll
        for (int i = 0; i < 2; ++i) {
            float fb[8] = {pf[i][0].x, pf[i][0].y, pf[i][0].z, pf[i][0].w,
                           pf[i][1].x, pf[i][1].y, pf[i][1].z, pf[i][1].w};
            cvt_split8_exact(fb, ah[i], al[i]);
        }
        // 3) issue next A (younger than this iter's stage)
        if (c + 1 < 16) {
            int kc = (c + 1) * 32;
            #pragma unroll
            for (int i = 0; i < 2; ++i) {
                pf[i][0] = *(const float4*)(abase + i * 16 * ENC_ + kc);
                pf[i][1] = *(const float4*)(abase + i * 16 * ENC_ + kc + 4);
            }
        }

        // 4) B fragments from LDS (conflict-free lane-contiguous b128) + MFMA
        #pragma unroll
        for (int j = 0; j < 8; ++j) {
            short8 bh = *(const short8*)&sB[cur][j * 512 + lane * 8];
            short8 bl = *(const short8*)&sB[cur][4096 + j * 512 + lane * 8];
            #pragma unroll
            for (int i = 0; i < 2; ++i) {
                acc[i][j] = __builtin_amdgcn_mfma_f32_16x16x32_bf16(ah[i], bh, acc[i][j], 0, 0, 0);
                acc[i][j] = __builtin_amdgcn_mfma_f32_16x16x32_bf16(ah[i], bl, acc[i][j], 0, 0, 0);
                acc[i][j] = __builtin_amdgcn_mfma_f32_16x16x32_bf16(al[i], bh, acc[i][j], 0, 0, 0);
            }
        }

        // 5) counted wait: stage(c+1) retired, A(c+1) stays in flight
        if (c + 1 < 16) {
            __builtin_amdgcn_sched_barrier(0);
            asm volatile("s_waitcnt vmcnt(4)");
            __builtin_amdgcn_sched_barrier(0);
            __builtin_amdgcn_s_barrier();
            cur ^= 1;
        }
    }

    // ---- loc conv as MFMA: A' Toeplitz built from sx in-register ----
    {
        short8 ah[2], al[2];
        #pragma unroll
        for (int i = 0; i < 2; ++i) {
            int base = w * 32 + i * 16 + lane15 + quad * 8;
            float xv[8];
            #pragma unroll
            for (int j2 = 0; j2 < 8; ++j2) xv[j2] = sx[base + j2];
            cvt_split8_exact(xv, ah[i], al[i]);
        }
        #pragma unroll
        for (int j = 0; j < 8; ++j) {
            int n = j * 16 + lane15;
            short8 bh = *(const short8*)(effh + n * 32 + quad * 8);
            short8 bl = *(const short8*)(effl + n * 32 + quad * 8);
            #pragma unroll
            for (int i = 0; i < 2; ++i) {
                acc[i][j] = __builtin_amdgcn_mfma_f32_16x16x32_bf16(ah[i], bh, acc[i][j], 0, 0, 0);
                acc[i][j] = __builtin_amdgcn_mfma_f32_16x16x32_bf16(ah[i], bl, acc[i][j], 0, 0, 0);
                acc[i][j] = __builtin_amdgcn_mfma_f32_16x16x32_bf16(al[i], bh, acc[i][j], 0, 0, 0);
            }
        }
    }

    // ---- energies: E[t] = sum_n vw[n]*tanhf(acc + q[n]) -> LDS se[128] ----
    float qv[8], vv[8];
    #pragma unroll
    for (int j = 0; j < 8; ++j) {
        int n = j * 16 + lane15;
        qv[j] = qbuf[b * ATT_ + n];
        vv[j] = vw[n];
    }
    #pragma unroll
    for (int i = 0; i < 2; ++i)
        #pragma unroll
        for (int r = 0; r < 4; ++r) {
            float s = 0.f;
            #pragma unroll
            for (int j = 0; j < 8; ++j)
                s += vv[j] * tanhf(acc[i][j][r] + qv[j]);
            #pragma unroll
            for (int m = 8; m >= 1; m >>= 1) s += __shfl_xor(s, m, 64);
            if (lane15 == 0)
                se[w * 32 + i * 16 + quad * 4 + r] = s;
        }
    __syncthreads();

    // ---- mask, then local (chunk) max + sum ----
    if (tid < 128 && mask[b * T_ + t0 + tid]) se[tid] = -INFINITY;
    __syncthreads();

    float e0 = se[lane * 2], e1 = se[lane * 2 + 1];
    float mx = fmaxf(e0, e1);
    #pragma unroll
    for (int m = 32; m >= 1; m >>= 1) mx = fmaxf(mx, __shfl_xor(mx, m, 64));
    float w0 = 0.f, w1 = 0.f;
    if (mx > -INFINITY) {
        w0 = expf(e0 - mx);
        w1 = expf(e1 - mx);
    }
    float sm = w0 + w1;
    #pragma unroll
    for (int m = 32; m >= 1; m >>= 1) sm += __shfl_xor(sm, m, 64);
    __syncthreads();

    if (w == 0) {
        se[lane * 2]     = w0;
        se[lane * 2 + 1] = w1;
        *(float2*)(wU + b * T_ + t0 + lane * 2) = make_float2(w0, w1);
        if (lane == 0)
            *(float2*)(bstats + bx * 2) = make_float2(mx, sm);
    }
    __syncthreads();

    // ---- partial context (chunk is L2/L3-resident) ----
    {
        int tt = tid >> 7;
        int e4 = (tid & 127) * 4;
        const float* vp = values + ((size_t)b * T_ + t0 + tt * 64) * ENC_ + e4;
        float4 cacc = make_float4(0.f, 0.f, 0.f, 0.f);
        #pragma unroll 8
        for (int t = 0; t < 64; ++t) {
            float4 v = *(const float4*)(vp + (size_t)t * ENC_);
            float wv = se[tt * 64 + t];
            cacc.x += wv * v.x; cacc.y += wv * v.y;
            cacc.z += wv * v.z; cacc.w += wv * v.w;
        }
        if (tt == 1) *(float4*)&red[e4] = cacc;
        __syncthreads();
        if (tt == 0) {
            float4 o = *(const float4*)&red[e4];
            float4 tot = make_float4(cacc.x + o.x, cacc.y + o.y,
                                     cacc.z + o.z, cacc.w + o.w);
            *(float4*)(ctxpart + (size_t)bx * ENC_ + e4) = tot;
        }
    }
}

// ---------------------------------------------------------------------------
// K3: combine 16 chunk-partials per b (unchanged)
// ---------------------------------------------------------------------------
__global__ __launch_bounds__(256) void combine_kernel(
    const float* __restrict__ bstats, const float* __restrict__ ctxpart,
    const float* __restrict__ wU, float* __restrict__ out)
{
    int b = blockIdx.x, tid = threadIdx.x;
    __shared__ float smx[16], ssm[16], ssc[16];
    if (tid < 16) {
        float2 st = *(const float2*)(bstats + (b * 16 + tid) * 2);
        smx[tid] = st.x; ssm[tid] = st.y;
    }
    __syncthreads();
    float M = -INFINITY;
    #pragma unroll
    for (int k = 0; k < 16; ++k) M = fmaxf(M, smx[k]);
    if (tid < 16)
        ssc[tid] = (smx[tid] > -INFINITY) ? expf(smx[tid] - M) : 0.f;
    __syncthreads();
    float S = 0.f;
    #pragma unroll
    for (int k = 0; k < 16; ++k) S += ssm[k] * ssc[k];
    float invS = 1.f / S;

    float* ctx  = out;
    float* wout = out + B_ * ENC_;

    float cx = 0.f, cy = 0.f;
    #pragma unroll
    for (int k = 0; k < 16; ++k) {
        float2 v = *(const float2*)(ctxpart + (size_t)(b * 16 + k) * ENC_ + tid * 2);
        cx += v.x * ssc[k]; cy += v.y * ssc[k];
    }
    *(float2*)(ctx + b * ENC_ + tid * 2) = make_float2(cx * invS, cy * invS);

    #pragma unroll
    for (int p = 0; p < 8; ++p) {
        int t = p * 256 + tid;
        wout[b * T_ + t] = wU[b * T_ + t] * ssc[t >> 7] * invS;
    }
}

// ---------------------------------------------------------------------------
extern "C" void kernel_launch(void* const* d_in, const int* in_sizes, int n_in,
                              void* d_out, int out_size, void* d_ws, size_t ws_size,
                              hipStream_t stream) {
    const float* query        = (const float*)d_in[0];
    const float* values       = (const float*)d_in[1];
    const float* cum          = (const float*)d_in[2];
    const unsigned char* mask = (const unsigned char*)d_in[3];
    const float* Q_w          = (const float*)d_in[4];
    const float* Q_b          = (const float*)d_in[5];
    const float* V_w          = (const float*)d_in[6];
    const float* conv_w       = (const float*)d_in[7];
    const float* loc_proj_w   = (const float*)d_in[8];
    const float* v_w          = (const float*)d_in[9];

    float* out = (float*)d_out;
    char*  ws  = (char*)d_ws;
    // ws layout (bytes):
    //  qbuf @0 (32 KB) | Bpk @32768 (256 KB, staging-order packed V_w hi/lo)
    //  effh @294912 (8 KB) | effl @303104 (8 KB) | wU @311296 (512 KB)
    //  bstats @835584 (8 KB) | ctxpart @843776 (2 MB)
    float*          qbuf     = (float*)(ws);
    unsigned short* Bpk      = (unsigned short*)(ws + 32768);
    unsigned short* effh     = (unsigned short*)(ws + 294912);
    unsigned short* effl     = (unsigned short*)(ws + 303104);
    float*          wU       = (float*)(ws + 311296);
    float*          bstats   = (float*)(ws + 835584);
    float*          ctxpart  = (float*)(ws + 843776);

    prep_kernel<<<289, 256, 0, stream>>>(query, Q_w, Q_b, conv_w, loc_proj_w, V_w,
                                         qbuf, Bpk, effh, effl);
    energy_ctx_kernel<<<1024, 256, 0, stream>>>(values, cum, qbuf, Bpk,
                                                effh, effl, v_w, mask,
                                                wU, bstats, ctxpart);
    combine_kernel<<<B_, 256, 0, stream>>>(bstats, ctxpart, wU, out);
}